// Round 3
// baseline (198.762 us; speedup 1.0000x reference)
//
#include <hip/hip_runtime.h>
#include <math.h>

// Problem constants (B=16, C=3 -> 48 planes of 512x512)
#define H_IMG 512
#define W_IMG 512
#define TW 32              // strip width (output cols per block)
#define CH 32              // output rows per chunk
#define NCHUNK 4           // chunks per block -> 128 output rows per block
#define STRIP (CH*NCHUNK)  // 128
#define HALO 5
#define WS11 11
#define RING 42            // ring rows: live window is 42 (32 new + 10 reused)
#define RS 36              // row stride in floats (32 cols + pad, 16B-aligned rows)
#define FSTR (RING*RS)     // 1512 floats per field
#define NTHREADS 256

typedef float f2 __attribute__((ext_vector_type(2)));

// Gaussian 11-tap, sigma=1.5, normalized; folds to literals after unroll.
// Out-of-range taps -> 0 so packed pairs can run harmlessly.
__host__ __device__ constexpr float WT(int t) {
    return (t==0||t==10) ? 0.00102838f :
           (t==1||t==9)  ? 0.00759873f :
           (t==2||t==8)  ? 0.03600075f :
           (t==3||t==7)  ? 0.10936070f :
           (t==4||t==6)  ? 0.21300556f :
           (t==5)        ? 0.26601172f : 0.0f;
}

static __device__ __forceinline__ f2 splat2(float v) { f2 r = {v, v}; return r; }

// Prefetch buffer: RAW loaded registers (no unpack at issue time, so no
// vmcnt wait until first FMA use at consume time).
struct Pre {
    float4 XA, XB, XC, XD; float XE;
    float4 YA, YB, YC, YD; float YE;
};

// Issue the global loads for one hconv task (row gy, 4 output cols at c0).
// xin is block-uniform; rok may diverge at image top/bottom only.
static __device__ __forceinline__ void issue_row(Pre& P,
        const float* __restrict__ xp, const float* __restrict__ yp,
        int gy, int tx0, int c0, bool xin, bool rok) {
    if (!rok) return;
    const size_t rowoff = (size_t)gy * W_IMG;
    if (xin) {
        // ga = bx*32 + c0 - 8 : 16B-aligned, in [24, 484]
        const float* rx = xp + rowoff + (tx0 + c0 - 3);
        const float* ry = yp + rowoff + (tx0 + c0 - 3);
        P.XA = *(const float4*)(rx);
        P.XB = *(const float4*)(rx + 4);
        P.XC = *(const float4*)(rx + 8);
        P.XD = *(const float4*)(rx + 12);
        P.XE = rx[16];
        P.YA = *(const float4*)(ry);
        P.YB = *(const float4*)(ry + 4);
        P.YC = *(const float4*)(ry + 8);
        P.YD = *(const float4*)(ry + 12);
        P.YE = ry[16];
    } else {
        const int gc = tx0 + c0;
        const float* prx = xp + rowoff + gc;
        const float* pry = yp + rowoff + gc;
        float t[14], u[14];
#pragma unroll
        for (int j = 0; j < 14; ++j) {
            bool ok = (unsigned)(gc + j) < (unsigned)W_IMG;
            t[j] = ok ? prx[j] : 0.f;
            u[j] = ok ? pry[j] : 0.f;
        }
        P.XA.w = t[0];
        P.XB.x = t[1];  P.XB.y = t[2];  P.XB.z = t[3];  P.XB.w = t[4];
        P.XC.x = t[5];  P.XC.y = t[6];  P.XC.z = t[7];  P.XC.w = t[8];
        P.XD.x = t[9];  P.XD.y = t[10]; P.XD.z = t[11]; P.XD.w = t[12];
        P.XE   = t[13];
        P.YA.w = u[0];
        P.YB.x = u[1];  P.YB.y = u[2];  P.YB.z = u[3];  P.YB.w = u[4];
        P.YC.x = u[5];  P.YC.y = u[6];  P.YC.z = u[7];  P.YC.w = u[8];
        P.YD.x = u[9];  P.YD.y = u[10]; P.YD.z = u[11]; P.YD.w = u[12];
        P.YE   = u[13];
    }
}

// Consume one prefetched task: fused MSE (if own), packed hconv of 5 fields,
// float4 write of 4 output cols into ring row wb.
static __device__ __forceinline__ void consume_row(const Pre& P,
        float* __restrict__ wb, bool rok, bool own, float& mse_acc) {
    if (!rok) {
        const float4 z = make_float4(0.f, 0.f, 0.f, 0.f);
#pragma unroll
        for (int f = 0; f < 5; ++f) *(float4*)(wb + f*FSTR) = z;
        return;
    }
    float xv[14], yv[14];
    xv[0]=P.XA.w;  xv[1]=P.XB.x;  xv[2]=P.XB.y;  xv[3]=P.XB.z;  xv[4]=P.XB.w;
    xv[5]=P.XC.x;  xv[6]=P.XC.y;  xv[7]=P.XC.z;  xv[8]=P.XC.w;  xv[9]=P.XD.x;
    xv[10]=P.XD.y; xv[11]=P.XD.z; xv[12]=P.XD.w; xv[13]=P.XE;
    yv[0]=P.YA.w;  yv[1]=P.YB.x;  yv[2]=P.YB.y;  yv[3]=P.YB.z;  yv[4]=P.YB.w;
    yv[5]=P.YC.x;  yv[6]=P.YC.y;  yv[7]=P.YC.z;  yv[8]=P.YC.w;  yv[9]=P.YD.x;
    yv[10]=P.YD.y; yv[11]=P.YD.z; yv[12]=P.YD.w; yv[13]=P.YE;

    if (own) {
#pragma unroll
        for (int j = 5; j < 9; ++j) {
            float d = xv[j] - yv[j];
            mse_acc = fmaf(d, d, mse_acc);
        }
    }

    f2 A[5][2];
#pragma unroll
    for (int f = 0; f < 5; ++f) { A[f][0] = splat2(0.f); A[f][1] = splat2(0.f); }
#pragma unroll
    for (int j = 0; j < 14; ++j) {
        float px = xv[j], py = yv[j];
        float pxx = px*px, pyy = py*py, pxy = px*py;
#pragma unroll
        for (int p = 0; p < 2; ++p) {
            const int t0 = j - 2*p;          // tap for m=2p; m=2p+1 uses t0-1
            if (t0 >= 0 && t0 <= WS11) {
                const f2 wp = {WT(t0), WT(t0-1)};
                A[0][p] = __builtin_elementwise_fma(wp, splat2(px),  A[0][p]);
                A[1][p] = __builtin_elementwise_fma(wp, splat2(py),  A[1][p]);
                A[2][p] = __builtin_elementwise_fma(wp, splat2(pxx), A[2][p]);
                A[3][p] = __builtin_elementwise_fma(wp, splat2(pyy), A[3][p]);
                A[4][p] = __builtin_elementwise_fma(wp, splat2(pxy), A[4][p]);
            }
        }
    }
#pragma unroll
    for (int f = 0; f < 5; ++f) {
        *(float4*)(wb + f*FSTR) =
            make_float4(A[f][0].x, A[f][0].y, A[f][1].x, A[f][1].y);
    }
}

// Column-strip kernel: block = 32 cols x 128 rows of one plane.
// Hconv rows (5 fields) live in a 42-row LDS ring; each image row is
// hconv'd once per block. Global loads for chunk k+1 are ISSUED right
// after chunk k's data is consumed, so their latency hides under
// Stage B + two barriers (T14 async-stage split).
__global__ __launch_bounds__(NTHREADS, 4) void ssim_mse_tile(
        const float* __restrict__ cover, const float* __restrict__ wmed,
        float* __restrict__ part, int nParts) {
    __shared__ __align__(16) float rbuf[5*FSTR];   // 30240 B

    const int tid = threadIdx.x;
    const int bx  = blockIdx.x & 15;          // x-strip
    const int ys  = (blockIdx.x >> 4) & 3;    // y quarter
    const int pl  = blockIdx.x >> 6;          // plane
    const size_t pbase = (size_t)pl * (H_IMG*W_IMG);
    const float* xp = wmed + pbase;           // x = wmed, y = cover
    const float* yp = cover + pbase;
    const int Y0  = ys << 7;                  // 0,128,256,384
    const int tx0 = bx*TW - HALO;
    const bool xin = (bx != 0) && (bx != 15); // fast-path columns

    const int rA = tid >> 3;                  // steady task row 0..31
    const int c0 = (tid & 7) << 2;            // task col group

    float ssim_acc = 0.f, mse_acc = 0.f;
    Pre P;

    // ---- Prologue: chunk 0 (42 rows = 336 tasks) + prefetch chunk 1 ----
    {
        Pre P0, P1;
        const int  hrA  = rA - HALO;                       // -5..26
        const int  gyA  = Y0 + hrA;
        const bool rokA = (unsigned)gyA < (unsigned)H_IMG;
        const bool two  = (tid < 80);                      // rows 32..41
        const int  gyB  = gyA + 32;
        const bool rokB = two && ((unsigned)gyB < (unsigned)H_IMG);
        issue_row(P0, xp, yp, gyA, tx0, c0, xin, rokA);
        if (two) issue_row(P1, xp, yp, gyB, tx0, c0, xin, rokB);
        consume_row(P0, &rbuf[rA*RS + c0], rokA, hrA >= 0, mse_acc);
        if (two) consume_row(P1, &rbuf[(rA+32)*RS + c0], rokB, true, mse_acc);
        // prefetch chunk 1 (rows hr = 37+rA)
        const int  gy1  = Y0 + CH + HALO + rA;
        const bool rok1 = (unsigned)gy1 < (unsigned)H_IMG;
        issue_row(P, xp, yp, gy1, tx0, c0, xin, rok1);
    }
    __syncthreads();

    int slotA = rA;                 // ring slot of next A row (chunk 1)
    int sbB   = (tid >> 5) << 2;    // Stage B base slot (chunk 0)

    for (int k = 0; k < NCHUNK; ++k) {
        // ---- Stage B: vertical 11-tap + SSIM; ALL 256 threads.
        //      Task = 4 output rows x 1 col; row-pair packed f2 accums,
        //      b32 LDS reads (bank-conflict-free, measured 0). ----
        {
            const int c = tid & 31;
            f2 acc[5][2];
#pragma unroll
            for (int f = 0; f < 5; ++f) {
                acc[f][0] = splat2(0.f); acc[f][1] = splat2(0.f);
            }
            const float* bp = rbuf + c;
#pragma unroll
            for (int i = 0; i < 14; ++i) {
                int sl = sbB + i; if (sl >= RING) sl -= RING;
                const float* rp = bp + sl*RS;
#pragma unroll
                for (int f = 0; f < 5; ++f) {
                    float v = rp[f*FSTR];
#pragma unroll
                    for (int p = 0; p < 2; ++p) {
                        const int t0 = i - 2*p;      // tap for row 2p; 2p+1 uses t0-1
                        if (t0 >= 0 && t0 <= WS11) {
                            const f2 wp = {WT(t0), WT(t0-1)};
                            acc[f][p] = __builtin_elementwise_fma(wp, splat2(v), acc[f][p]);
                        }
                    }
                }
            }
            const f2 c1v = {1e-4f, 1e-4f};
            const f2 c2v = {9e-4f, 9e-4f};
            const f2 two2 = {2.f, 2.f};
#pragma unroll
            for (int p = 0; p < 2; ++p) {
                f2 mx = acc[0][p], my = acc[1][p];
                f2 sxx = acc[2][p] - mx*mx;
                f2 syy = acc[3][p] - my*my;
                f2 sxy = acc[4][p] - mx*my;
                f2 num = (two2*mx*my + c1v) * (two2*sxy + c2v);
                f2 den = (mx*mx + my*my + c1v) * (sxx + syy + c2v);
                ssim_acc += __fdividef(num.x, den.x) + __fdividef(num.y, den.y);
            }
        }

        if (k + 1 < NCHUNK) {
            __syncthreads();   // B(k) reads done before A(k+1) overwrites
            // ---- Stage A(k+1): consume prefetched chunk, issue chunk k+2 ----
            const int  hr  = CH*(k+1) + HALO + rA;
            const int  gy  = Y0 + hr;
            const bool rok = (unsigned)gy < (unsigned)H_IMG;
            consume_row(P, &rbuf[slotA*RS + c0], rok, hr < STRIP, mse_acc);
            if (k + 2 < NCHUNK) {
                const int  gy2  = gy + CH;
                const bool rok2 = (unsigned)gy2 < (unsigned)H_IMG;
                issue_row(P, xp, yp, gy2, tx0, c0, xin, rok2);
            }
            slotA += CH; if (slotA >= RING) slotA -= RING;
            sbB   += CH; if (sbB   >= RING) sbB   -= RING;
            __syncthreads();   // A(k+1) writes visible to B(k+1)
        }
    }
    __syncthreads();   // all B(3) LDS reads done before scratch reuse

    // ---- Block reduce (4 waves of 64); reuse rbuf as scratch ----
#pragma unroll
    for (int off = 32; off > 0; off >>= 1) {
        ssim_acc += __shfl_down(ssim_acc, off);
        mse_acc  += __shfl_down(mse_acc, off);
    }
    const int wid = tid >> 6, lane = tid & 63;
    if (lane == 0) { rbuf[wid] = ssim_acc; rbuf[4+wid] = mse_acc; }
    __syncthreads();
    if (tid == 0) {
        part[blockIdx.x] = rbuf[0]+rbuf[1]+rbuf[2]+rbuf[3];
        part[nParts + blockIdx.x] = rbuf[4]+rbuf[5]+rbuf[6]+rbuf[7];
    }
}

// 1024-thread finalize: vectorized partial reduce (double), fast-log BCE,
// curriculum weights.
#define FT 1024
__global__ __launch_bounds__(FT) void finalize_k(
        const float* __restrict__ part, int nParts,
        const float* __restrict__ wm_orig, const float* __restrict__ wm_ext,
        int nWm, const int* __restrict__ epoch_p,
        float* __restrict__ out, double inv_npix, double inv_nwm) {
    __shared__ double red[48];
    int tid = threadIdx.x;
    double s_ssim = 0.0, s_mse = 0.0, s_wl = 0.0;
    const float4* s4 = (const float4*)part;
    const float4* m4 = (const float4*)(part + nParts);
    int n4 = nParts >> 2;
    for (int i = tid; i < n4; i += FT) {
        float4 v = s4[i];
        s_ssim += (double)((v.x + v.y) + (v.z + v.w));
        float4 u = m4[i];
        s_mse  += (double)((u.x + u.y) + (u.z + u.w));
    }
    const float4* p4 = (const float4*)wm_orig;
    const float4* q4 = (const float4*)wm_ext;
    int w4 = nWm >> 2;
    for (int i = tid; i < w4; i += FT) {
        float4 p = p4[i], q = q4[i];
        float a;
        a  = -(p.x*__logf(q.x) + (1.f-p.x)*__logf(1.f-q.x));
        a += -(p.y*__logf(q.y) + (1.f-p.y)*__logf(1.f-q.y));
        a += -(p.z*__logf(q.z) + (1.f-p.z)*__logf(1.f-q.z));
        a += -(p.w*__logf(q.w) + (1.f-p.w)*__logf(1.f-q.w));
        s_wl += (double)a;
    }
#pragma unroll
    for (int off = 32; off > 0; off >>= 1) {
        s_ssim += __shfl_down(s_ssim, off);
        s_mse  += __shfl_down(s_mse, off);
        s_wl   += __shfl_down(s_wl, off);
    }
    int wid = tid >> 6, lane = tid & 63;
    if (lane == 0) { red[wid] = s_ssim; red[16+wid] = s_mse; red[32+wid] = s_wl; }
    __syncthreads();
    if (tid == 0) {
        double ssim_sum = 0.0, mse_sum = 0.0, wl_sum = 0.0;
        for (int i = 0; i < 16; ++i) {
            ssim_sum += red[i]; mse_sum += red[16+i]; wl_sum += red[32+i];
        }
        float sv = (float)(ssim_sum * inv_npix);
        float ml = (float)(mse_sum  * inv_npix);
        float wl = (float)(wl_sum   * inv_nwm);
        int e = *epoch_p;
        float w_img, w_ssim;
        if (e <= 12) {
            w_img = 0.05f; w_ssim = 0.05f;
        } else {
            float progress = fminf(1.0f, (float)(e - 12) / 10.0f);
            w_img  = 0.05f + (0.5f - 0.05f)*progress;
            w_ssim = 0.05f + (0.8f - 0.05f)*progress;
        }
        float sl = 1.0f - sv;
        float total = w_img*ml + w_ssim*sl + 3.0f*wl;
        out[0] = total;
        out[1] = ml;
        out[2] = sv;
        out[3] = wl;
    }
}

extern "C" void kernel_launch(void* const* d_in, const int* in_sizes, int n_in,
                              void* d_out, int out_size, void* d_ws, size_t ws_size,
                              hipStream_t stream) {
    const float* cover   = (const float*)d_in[0];
    const float* wmed    = (const float*)d_in[1];
    const float* wm_orig = (const float*)d_in[2];
    const float* wm_ext  = (const float*)d_in[3];
    const int*   epoch   = (const int*)d_in[4];
    float* out = (float*)d_out;

    int npix   = in_sizes[0];                 // 12,582,912
    int planes = npix / (H_IMG * W_IMG);      // 48
    int nWm    = in_sizes[2];                 // 16,384

    int nBlocks = 16 * 4 * planes;            // 3072 column-strip blocks
    int nParts  = nBlocks;
    float* part = (float*)d_ws;               // 2 * nParts floats (24 KB)

    ssim_mse_tile<<<nBlocks, NTHREADS, 0, stream>>>(cover, wmed, part, nParts);
    finalize_k<<<1, FT, 0, stream>>>(part, nParts, wm_orig, wm_ext, nWm,
                                     epoch, out,
                                     1.0 / (double)npix, 1.0 / (double)nWm);
}